// Round 1
// 196.114 us; speedup vs baseline: 1.0296x; 1.0296x over previous
//
#include <hip/hip_runtime.h>
#include <stdint.h>

#define N_NODES 100000
#define N_FEAT 128
#define N_EDGES 3200000

// ---------- bf16 helpers ----------
static __device__ __forceinline__ unsigned int f2bf_u(float f) {
    unsigned int u = __float_as_uint(f);
    u += 0x7FFFu + ((u >> 16) & 1u);   // RNE
    return u >> 16;
}

typedef __bf16 bf16x8 __attribute__((ext_vector_type(8)));
typedef float f32x4 __attribute__((ext_vector_type(4)));

// ---------- Kernel 1 (prep): CSR row_ptr + filters -> bf16 fragment-linear ----------
// blocks [0,12500):      CSR row_ptr scatter from sorted edge_dst
// blocks [12500,12564):  filters -> bf16 in MFMA B-fragment-linear order:
//   flat short index i: s=i&7, lane=(i>>3)&63, kkidx=(i>>9)&3, j=i>>11
//   holds F[k][n] with n = j*16 + (lane&15), k = kkidx*32 + (lane>>4)*8 + s
__global__ __launch_bounds__(256) void k_prep(
        const float* __restrict__ f, unsigned short* __restrict__ fB,
        const int* __restrict__ dst, int* __restrict__ row_ptr) {
    int b = blockIdx.x;
    if (b < 12500) {
        int e = b * 256 + threadIdx.x;
        if (e >= N_EDGES) return;
        int dcur = dst[e];
        if (e == 0) {
            for (int d = 0; d <= dcur; ++d) row_ptr[d] = 0;
        } else {
            int dprev = dst[e - 1];
            for (int d = dprev + 1; d <= dcur; ++d) row_ptr[d] = e;
        }
        if (e == N_EDGES - 1) {
            for (int d = dcur + 1; d <= N_NODES; ++d) row_ptr[d] = N_EDGES;
        }
    } else {
        int i = (b - 12500) * 256 + threadIdx.x;   // flat fragment-linear index
        if (i >= N_FEAT * N_FEAT) return;
        int n = ((i >> 11) << 4) | ((i >> 3) & 15);
        int k = (((i >> 9) & 3) << 5) | (((i >> 7) & 3) << 3) | (i & 7);
        fB[i] = (unsigned short)f2bf_u(f[k * 128 + n]);
    }
}

// ---------- Kernel 2: XF = x @ F (MFMA), fused biased-uint8 row quantization ----------
// Block 256 (4 waves), 64 rows/block. B in LDS fragment-linear (32KB, 5 blocks/CU).
// A loaded fp32 straight from global (16 rows x 128B per kkidx), converted to bf16.
// Epilogue: per-row absmax over 16 lanes -> q_u = rint(v*127/max)+128 in [1,255].
// Packed layout: byte b of uint c of a row = feature (b*32 + c).
//   acc[j][r] = XF[rowbase + q*4 + r][j*16 + m15]; feature 32b+c on lane m15=c&15,
//   j = 2b + (c>=16). So lane m15 packs uints c=m15 (j even) and c=m15+16 (j odd).
__global__ __launch_bounds__(256) void k_xf(
        const float* __restrict__ x,
        const unsigned short* __restrict__ fB,
        unsigned int* __restrict__ xi8,          // [N][32] uints (4 biased-u8 each)
        float* __restrict__ xscale) {            // [N]
    __shared__ unsigned short Bbuf[16384];       // 32768 B exactly
    int t = threadIdx.x;
    for (int i = 0; i < 8; ++i)
        ((uint4*)Bbuf)[t + i * 256] = ((const uint4*)fB)[t + i * 256];
    __syncthreads();

    int wave = t >> 6, lane = t & 63, m15 = lane & 15, q = lane >> 4;
    int row = blockIdx.x * 64 + wave * 16 + m15;
    int rowc = min(row, N_NODES - 1);            // clamp loads; stores guarded

    f32x4 acc[8];
#pragma unroll
    for (int j = 0; j < 8; ++j) acc[j] = f32x4{0.f, 0.f, 0.f, 0.f};

#pragma unroll
    for (int kkidx = 0; kkidx < 4; ++kkidx) {
        const float* ap = x + (size_t)rowc * 128 + kkidx * 32 + q * 8;
        float4 v0 = *(const float4*)ap;
        float4 v1 = *(const float4*)(ap + 4);
        union { bf16x8 v; unsigned short s[8]; } au;
        au.s[0] = (unsigned short)f2bf_u(v0.x);
        au.s[1] = (unsigned short)f2bf_u(v0.y);
        au.s[2] = (unsigned short)f2bf_u(v0.z);
        au.s[3] = (unsigned short)f2bf_u(v0.w);
        au.s[4] = (unsigned short)f2bf_u(v1.x);
        au.s[5] = (unsigned short)f2bf_u(v1.y);
        au.s[6] = (unsigned short)f2bf_u(v1.z);
        au.s[7] = (unsigned short)f2bf_u(v1.w);
#pragma unroll
        for (int j = 0; j < 8; ++j) {
            bf16x8 bfrag = *(const bf16x8*)(Bbuf + (((j * 4 + kkidx) * 64 + lane) * 8));
            acc[j] = __builtin_amdgcn_mfma_f32_16x16x32_bf16(au.v, bfrag, acc[j], 0, 0, 0);
        }
    }

    int rowbase = blockIdx.x * 64 + wave * 16 + q * 4;   // D: row=q*4+r, col=j*16+m15
#pragma unroll
    for (int r = 0; r < 4; ++r) {
        float mx = 0.f;
#pragma unroll
        for (int j = 0; j < 8; ++j) mx = fmaxf(mx, fabsf(acc[j][r]));
        for (int d = 1; d < 16; d <<= 1) mx = fmaxf(mx, __shfl_xor(mx, d));
        float inv = 127.f / fmaxf(mx, 1e-20f);
        unsigned int u0 = 0, u1 = 0;
#pragma unroll
        for (int bb = 0; bb < 4; ++bb) {
            unsigned int q0 = (unsigned int)(int)(rintf(acc[2 * bb][r] * inv) + 128.f);
            unsigned int q1 = (unsigned int)(int)(rintf(acc[2 * bb + 1][r] * inv) + 128.f);
            u0 |= (q0 & 0xFFu) << (8 * bb);
            u1 |= (q1 & 0xFFu) << (8 * bb);
        }
        int gr = rowbase + r;
        if (gr < N_NODES) {
            xi8[(size_t)gr * 32 + m15] = u0;
            xi8[(size_t)gr * 32 + 16 + m15] = u1;
            if (m15 == 0) xscale[gr] = mx * (1.f / 127.f);
        }
    }
}

// ---------- Kernel 3: out[d] = sum_e w_e * xscale[s] * (q_u - 128) -> fp32 direct ----------
// Biased-u8 unpack via v_cvt_f32_ubyteN pattern; -128 bias corrected once per edge
// through the aw (sum of folded weights) accumulator -- exact integer offset.
__global__ __launch_bounds__(256) void k_aggregate(
        const unsigned int* __restrict__ xi8,    // [N][32] uints (4 biased-u8 each)
        const float* __restrict__ xscale,        // [N]
        const int* __restrict__ src,
        const float* __restrict__ w,
        const int* __restrict__ row_ptr,
        float* __restrict__ out) {               // [N][128] fp32 (final output)
    __shared__ uint2 smeta[4][64];
    int wave = threadIdx.x >> 6, lane = threadIdx.x & 63;
    int node = blockIdx.x * 4 + wave;
    if (node >= N_NODES) return;
    int half = lane >> 5, f = lane & 31;
    int start = row_ptr[node], end = row_ptr[node + 1];
    float a0 = 0.f, a1 = 0.f, a2 = 0.f, a3 = 0.f, aw = 0.f;

    for (int e0 = start; e0 < end; e0 += 64) {
        int e = e0 + lane;
        uint2 m = make_uint2(0u, 0u);                    // pad: src=0, w'=0
        if (e < end) {
            int sv = src[e];
            m.x = (unsigned int)sv;
            m.y = __float_as_uint(w[e] * xscale[sv]);    // fold row scale
        }
        smeta[wave][lane] = m;                           // wave-private; no barrier
        int cnt16 = (min(64, end - e0) + 15) & ~15;
        for (int j = 0; j < cnt16; j += 16) {
            unsigned int vv[8]; float wj[8];
#pragma unroll
            for (int u = 0; u < 8; ++u) {
                uint2 mm = smeta[wave][j + u * 2 + half];
                wj[u] = __uint_as_float(mm.y);
                vv[u] = xi8[mm.x * 32 + f];              // 2 edges x 128B / wave
            }
#pragma unroll
            for (int u = 0; u < 8; ++u) {
                a0 = fmaf(wj[u], (float)( vv[u]         & 0xFFu), a0);
                a1 = fmaf(wj[u], (float)((vv[u] >>  8)  & 0xFFu), a1);
                a2 = fmaf(wj[u], (float)((vv[u] >> 16)  & 0xFFu), a2);
                a3 = fmaf(wj[u], (float)( vv[u] >> 24          ), a3);
                aw += wj[u];
            }
        }
    }
    // undo the +128 bias (exact: sum of 128*W folded through aw)
    a0 = fmaf(-128.f, aw, a0);
    a1 = fmaf(-128.f, aw, a1);
    a2 = fmaf(-128.f, aw, a2);
    a3 = fmaf(-128.f, aw, a3);

    a0 += __shfl_xor(a0, 32);
    a1 += __shfl_xor(a1, 32);
    a2 += __shfl_xor(a2, 32);
    a3 += __shfl_xor(a3, 32);
    if (half == 0) {
        float* o = out + (size_t)node * 128 + f;
        o[ 0] = a0;
        o[32] = a1;
        o[64] = a2;
        o[96] = a3;
    }
}

extern "C" void kernel_launch(void* const* d_in, const int* in_sizes, int n_in,
                              void* d_out, int out_size, void* d_ws, size_t ws_size,
                              hipStream_t stream) {
    const float* x        = (const float*)d_in[0];
    const float* filters  = (const float*)d_in[1];
    const int*   edge_src = (const int*)d_in[2];
    const int*   edge_dst = (const int*)d_in[3];
    const float* edge_w   = (const float*)d_in[4];
    float* out = (float*)d_out;

    char* ws = (char*)d_ws;
    unsigned int*   xi8 = (unsigned int*)  (ws);                          // 12.8 MB
    float*          xsc = (float*)         (ws + 13ll * 1024 * 1024);     // 400 KB
    unsigned short* fB  = (unsigned short*)(ws + 14ll * 1024 * 1024);     // 32 KB
    int*            rp  = (int*)           (ws + 15ll * 1024 * 1024);     // 400 KB

    hipLaunchKernelGGL(k_prep, dim3(12564), dim3(256), 0, stream,
                       filters, fB, edge_dst, rp);
    hipLaunchKernelGGL(k_xf, dim3(1563), dim3(256), 0, stream,
                       x, fB, xi8, xsc);
    hipLaunchKernelGGL(k_aggregate, dim3(25000), dim3(256), 0, stream,
                       xi8, xsc, edge_src, edge_w, rp, out);
}